// Round 3
// baseline (238.644 us; speedup 1.0000x reference)
//
#include <hip/hip_runtime.h>
#include <math.h>

#define DDIM 512
#define BDIM 256
#define NCLS 85742
#define NB 2048
#define N4 ((size_t)NCLS * 128)        // float4 elements in W (10,974,976)
#define STRIDE ((size_t)NB * 256)      // float4 grid stride (524,288)

__device__ __forceinline__ float wave_reduce(float v) {
    #pragma unroll
    for (int off = 32; off > 0; off >>= 1)
        v += __shfl_down(v, off, 64);
    return v;
}

__device__ __forceinline__ float block_reduce(float v, float* smem) {
    const int lane = threadIdx.x & 63;
    const int wid  = threadIdx.x >> 6;
    v = wave_reduce(v);
    if (lane == 0) smem[wid] = v;
    __syncthreads();
    if (wid == 0) {
        v = (lane < (int)(blockDim.x >> 6)) ? smem[lane] : 0.0f;
        v = wave_reduce(v);
    }
    return v;
}

// K1: colsum[d] = sum_c W[c][d].
// Flat float4 grid-stride: index i ≡ t (mod 128) always, so thread t owns
// fixed column-quad t&127. 2048 blocks = 32 waves/CU (full occupancy);
// 4 accumulators / 4 loads in flight (fits in <64 VGPR).
__global__ __launch_bounds__(256, 8)
void colsum_kernel(const float* __restrict__ W, float* __restrict__ colsum) {
    const int t = threadIdx.x;
    const float4* __restrict__ W4 = reinterpret_cast<const float4*>(W);

    float4 a0 = make_float4(0.f, 0.f, 0.f, 0.f);
    float4 a1 = a0, a2 = a0, a3 = a0;

    size_t i = (size_t)blockIdx.x * 256 + t;
    for (; i + 3 * STRIDE < N4; i += 4 * STRIDE) {
        float4 v0 = W4[i];
        float4 v1 = W4[i + STRIDE];
        float4 v2 = W4[i + 2 * STRIDE];
        float4 v3 = W4[i + 3 * STRIDE];
        a0.x += v0.x; a0.y += v0.y; a0.z += v0.z; a0.w += v0.w;
        a1.x += v1.x; a1.y += v1.y; a1.z += v1.z; a1.w += v1.w;
        a2.x += v2.x; a2.y += v2.y; a2.z += v2.z; a2.w += v2.w;
        a3.x += v3.x; a3.y += v3.y; a3.z += v3.z; a3.w += v3.w;
    }
    for (; i < N4; i += STRIDE) {
        float4 v = W4[i];
        a0.x += v.x; a0.y += v.y; a0.z += v.z; a0.w += v.w;
    }

    float4 acc;
    acc.x = (a0.x + a1.x) + (a2.x + a3.x);
    acc.y = (a0.y + a1.y) + (a2.y + a3.y);
    acc.z = (a0.z + a1.z) + (a2.z + a3.z);
    acc.w = (a0.w + a1.w) + (a2.w + a3.w);

    __shared__ float4 smem[128];
    const int col4 = t & 127;
    if (t >= 128) smem[col4] = acc;
    __syncthreads();
    if (t < 128) {
        float4 o = smem[col4];
        atomicAdd(&colsum[col4 * 4 + 0], acc.x + o.x);
        atomicAdd(&colsum[col4 * 4 + 1], acc.y + o.y);
        atomicAdd(&colsum[col4 * 4 + 2], acc.z + o.z);
        atomicAdd(&colsum[col4 * 4 + 3], acc.w + o.w);
    }
}

// K2: Sy = sum (wy-mu)^2 ; Si = sum (colsum - wy - mu)^2   over B*D elements
__global__ void dist_kernel(const float* __restrict__ mu,
                            const float* __restrict__ W,
                            const int*   __restrict__ label,
                            const float* __restrict__ colsum,
                            float* __restrict__ sums) {
    __shared__ float smem[8];
    float dy2 = 0.0f, di2 = 0.0f;
    const int n = BDIM * DDIM;
    for (int i = blockIdx.x * blockDim.x + threadIdx.x; i < n;
         i += gridDim.x * blockDim.x) {
        const int b = i >> 9;        // i / 512
        const int d = i & 511;       // i % 512
        const float w = W[(size_t)label[b] * DDIM + d];
        const float m = mu[i];
        const float a = w - m;
        dy2 += a * a;
        const float c = colsum[d] - w - m;
        di2 += c * c;
    }
    dy2 = block_reduce(dy2, smem);
    __syncthreads();
    di2 = block_reduce(di2, smem);
    if (threadIdx.x == 0) {
        atomicAdd(&sums[0], dy2);
        atomicAdd(&sums[1], di2);
    }
}

// K3: loss = sum erf(dy/(sqrt2*std)) + erfc(di/(sqrt2*std))
__global__ void loss_kernel(const float* __restrict__ stdv,
                            const float* __restrict__ sums,
                            float* __restrict__ out) {
    __shared__ float smem[8];
    const float dy = sqrtf(sums[0]);
    const float di = sqrtf(sums[1]);
    const float inv_sqrt2 = 0.70710678118654752f;
    float acc = 0.0f;
    const int n = BDIM * DDIM;
    for (int i = blockIdx.x * blockDim.x + threadIdx.x; i < n;
         i += gridDim.x * blockDim.x) {
        const float s = stdv[i];
        const float r = inv_sqrt2 / s;
        acc += erff(dy * r) + erfcf(di * r);
    }
    acc = block_reduce(acc, smem);
    if (threadIdx.x == 0) atomicAdd(out, acc);
}

extern "C" void kernel_launch(void* const* d_in, const int* in_sizes, int n_in,
                              void* d_out, int out_size, void* d_ws, size_t ws_size,
                              hipStream_t stream) {
    // inputs: 0=x (unused), 1=mu, 2=std, 3=weight, 4=label
    const float* mu    = (const float*)d_in[1];
    const float* stdv  = (const float*)d_in[2];
    const float* W     = (const float*)d_in[3];
    const int*   label = (const int*)d_in[4];
    float* out = (float*)d_out;
    float* ws  = (float*)d_ws;   // ws[0..511]=colsum, ws[512]=Sy, ws[513]=Si

    hipMemsetAsync(d_ws, 0, (DDIM + 2) * sizeof(float), stream);
    hipMemsetAsync(d_out, 0, sizeof(float), stream);

    colsum_kernel<<<NB, 256, 0, stream>>>(W, ws);
    dist_kernel<<<256, 256, 0, stream>>>(mu, W, label, ws, ws + DDIM);
    loss_kernel<<<256, 256, 0, stream>>>(stdv, ws + DDIM, out);
}

// Round 4
// 56.244 us; speedup vs baseline: 4.2430x; 4.2430x over previous
//
#include <hip/hip_runtime.h>
#include <math.h>

#define DDIM 512
#define BDIM 256
#define NCLS 85742
#define NB1 1024
#define CHUNK1 ((NCLS + NB1 - 1) / NB1)   // 84 rows per block

__device__ __forceinline__ float wave_reduce(float v) {
    #pragma unroll
    for (int off = 32; off > 0; off >>= 1)
        v += __shfl_down(v, off, 64);
    return v;
}

__device__ __forceinline__ float block_reduce(float v, float* smem) {
    const int lane = threadIdx.x & 63;
    const int wid  = threadIdx.x >> 6;
    v = wave_reduce(v);
    if (lane == 0) smem[wid] = v;
    __syncthreads();
    if (wid == 0) {
        v = (lane < (int)(blockDim.x >> 6)) ? smem[lane] : 0.0f;
        v = wave_reduce(v);
    }
    return v;
}

// K1: per-block column partial sums over a contiguous 84-row chunk.
// thread t: quad q=t&127, row parity rsub=t>>7. 2-deep ILP (2 float4 accums).
// Partials stored TRANSPOSED: partialT[q*NB1 + b], so K2 reads contiguously.
// No atomics.
__global__ __launch_bounds__(256, 4)
void colsum_partial(const float* __restrict__ W, float4* __restrict__ partialT) {
    const int t = threadIdx.x;
    const int q = t & 127;
    const int rsub = t >> 7;
    const int b = blockIdx.x;
    const float4* __restrict__ W4 = reinterpret_cast<const float4*>(W);

    const int r0 = b * CHUNK1;
    const int r1 = (r0 + CHUNK1 < NCLS) ? r0 + CHUNK1 : NCLS;

    float4 a0 = make_float4(0.f, 0.f, 0.f, 0.f);
    float4 a1 = make_float4(0.f, 0.f, 0.f, 0.f);
    int r = r0 + rsub;
    for (; r + 2 < r1; r += 4) {
        float4 v0 = W4[(size_t)r * 128 + q];
        float4 v1 = W4[(size_t)(r + 2) * 128 + q];
        a0.x += v0.x; a0.y += v0.y; a0.z += v0.z; a0.w += v0.w;
        a1.x += v1.x; a1.y += v1.y; a1.z += v1.z; a1.w += v1.w;
    }
    for (; r < r1; r += 2) {
        float4 v = W4[(size_t)r * 128 + q];
        a0.x += v.x; a0.y += v.y; a0.z += v.z; a0.w += v.w;
    }
    a0.x += a1.x; a0.y += a1.y; a0.z += a1.z; a0.w += a1.w;

    __shared__ float4 smem[128];
    if (rsub) smem[q] = a0;
    __syncthreads();
    if (!rsub) {
        float4 o = smem[q];
        a0.x += o.x; a0.y += o.y; a0.z += o.z; a0.w += o.w;
        partialT[(size_t)q * NB1 + b] = a0;   // empty blocks write zeros
    }
}

// K2: colsum quad q = sum of partialT[q*NB1 .. q*NB1+1023]. 128 blocks.
__global__ __launch_bounds__(256, 4)
void colsum_reduce(const float4* __restrict__ partialT, float* __restrict__ colsum) {
    const int q = blockIdx.x;       // 0..127
    const int t = threadIdx.x;
    const float4* __restrict__ p = partialT + (size_t)q * NB1;
    float4 v0 = p[t], v1 = p[t + 256], v2 = p[t + 512], v3 = p[t + 768];
    float sx = (v0.x + v1.x) + (v2.x + v3.x);
    float sy = (v0.y + v1.y) + (v2.y + v3.y);
    float sz = (v0.z + v1.z) + (v2.z + v3.z);
    float sw = (v0.w + v1.w) + (v2.w + v3.w);
    sx = wave_reduce(sx); sy = wave_reduce(sy);
    sz = wave_reduce(sz); sw = wave_reduce(sw);
    __shared__ float4 sm[4];
    if ((t & 63) == 0) sm[t >> 6] = make_float4(sx, sy, sz, sw);
    __syncthreads();
    if (t == 0) {
        float4 r0 = sm[0], r1 = sm[1], r2 = sm[2], r3 = sm[3];
        colsum[q * 4 + 0] = (r0.x + r1.x) + (r2.x + r3.x);
        colsum[q * 4 + 1] = (r0.y + r1.y) + (r2.y + r3.y);
        colsum[q * 4 + 2] = (r0.z + r1.z) + (r2.z + r3.z);
        colsum[q * 4 + 3] = (r0.w + r1.w) + (r2.w + r3.w);
    }
}

// K3: Sy = sum (wy-mu)^2 ; Si = sum (colsum - wy - mu)^2   over B*D elements
__global__ void dist_kernel(const float* __restrict__ mu,
                            const float* __restrict__ W,
                            const int*   __restrict__ label,
                            const float* __restrict__ colsum,
                            float* __restrict__ sums) {
    __shared__ float smem[8];
    float dy2 = 0.0f, di2 = 0.0f;
    const int n = BDIM * DDIM;
    for (int i = blockIdx.x * blockDim.x + threadIdx.x; i < n;
         i += gridDim.x * blockDim.x) {
        const int b = i >> 9;        // i / 512
        const int d = i & 511;       // i % 512
        const float w = W[(size_t)label[b] * DDIM + d];
        const float m = mu[i];
        const float a = w - m;
        dy2 += a * a;
        const float c = colsum[d] - w - m;
        di2 += c * c;
    }
    dy2 = block_reduce(dy2, smem);
    __syncthreads();
    di2 = block_reduce(di2, smem);
    if (threadIdx.x == 0) {
        atomicAdd(&sums[0], dy2);
        atomicAdd(&sums[1], di2);
    }
}

// K4: loss = sum erf(dy/(sqrt2*std)) + erfc(di/(sqrt2*std))
__global__ void loss_kernel(const float* __restrict__ stdv,
                            const float* __restrict__ sums,
                            float* __restrict__ out) {
    __shared__ float smem[8];
    const float dy = sqrtf(sums[0]);
    const float di = sqrtf(sums[1]);
    const float inv_sqrt2 = 0.70710678118654752f;
    float acc = 0.0f;
    const int n = BDIM * DDIM;
    for (int i = blockIdx.x * blockDim.x + threadIdx.x; i < n;
         i += gridDim.x * blockDim.x) {
        const float s = stdv[i];
        const float r = inv_sqrt2 / s;
        acc += erff(dy * r) + erfcf(di * r);
    }
    acc = block_reduce(acc, smem);
    if (threadIdx.x == 0) atomicAdd(out, acc);
}

extern "C" void kernel_launch(void* const* d_in, const int* in_sizes, int n_in,
                              void* d_out, int out_size, void* d_ws, size_t ws_size,
                              hipStream_t stream) {
    // inputs: 0=x (unused), 1=mu, 2=std, 3=weight, 4=label
    const float* mu    = (const float*)d_in[1];
    const float* stdv  = (const float*)d_in[2];
    const float* W     = (const float*)d_in[3];
    const int*   label = (const int*)d_in[4];
    float* out = (float*)d_out;
    float* ws  = (float*)d_ws;
    // ws layout: [0..511]=colsum, [512],[513]=Sy,Si, floats [1024 ...) = partialT (2 MB)
    float4* partialT = (float4*)(ws + 1024);

    hipMemsetAsync(d_ws, 0, 516 * sizeof(float), stream);
    hipMemsetAsync(d_out, 0, sizeof(float), stream);

    colsum_partial<<<NB1, 256, 0, stream>>>(W, partialT);
    colsum_reduce<<<128, 256, 0, stream>>>(partialT, ws);
    dist_kernel<<<256, 256, 0, stream>>>(mu, W, label, ws, ws + 512);
    loss_kernel<<<256, 256, 0, stream>>>(stdv, ws + 512, out);
}

// Round 5
// 50.081 us; speedup vs baseline: 4.7651x; 1.1231x over previous
//
#include <hip/hip_runtime.h>
#include <math.h>

#define DDIM 512
#define BDIM 256
#define NCLS 85742
#define NB1 1024
#define CHUNK1 ((NCLS + NB1 - 1) / NB1)   // 84 rows per block

__device__ __forceinline__ float wave_reduce(float v) {
    #pragma unroll
    for (int off = 32; off > 0; off >>= 1)
        v += __shfl_down(v, off, 64);
    return v;
}

__device__ __forceinline__ float block_reduce(float v, float* smem) {
    const int lane = threadIdx.x & 63;
    const int wid  = threadIdx.x >> 6;
    v = wave_reduce(v);
    if (lane == 0) smem[wid] = v;
    __syncthreads();
    if (wid == 0) {
        v = (lane < (int)(blockDim.x >> 6)) ? smem[lane] : 0.0f;
        v = wave_reduce(v);
    }
    return v;
}

// K1: per-block column partial sums over a contiguous 84-row chunk.
// thread t: quad q=t&127, row parity rsub=t>>7. 4-deep ILP (4 float4 accums,
// 4 loads in flight; ~40 VGPR, fits the 128-VGPR cap of launch_bounds(256,4)).
// Partials stored TRANSPOSED: partialT[q*NB1 + b] so K2 reads contiguously.
__global__ __launch_bounds__(256, 4)
void colsum_partial(const float* __restrict__ W, float4* __restrict__ partialT) {
    const int t = threadIdx.x;
    const int q = t & 127;
    const int rsub = t >> 7;
    const int b = blockIdx.x;
    const float4* __restrict__ W4 = reinterpret_cast<const float4*>(W);

    const int r0 = b * CHUNK1;
    const int r1 = (r0 + CHUNK1 < NCLS) ? r0 + CHUNK1 : NCLS;

    float4 a0 = make_float4(0.f, 0.f, 0.f, 0.f);
    float4 a1 = a0, a2 = a0, a3 = a0;
    int r = r0 + rsub;                       // rows stride 2 (parity split)
    for (; r + 6 < r1; r += 8) {
        float4 v0 = W4[(size_t)(r    ) * 128 + q];
        float4 v1 = W4[(size_t)(r + 2) * 128 + q];
        float4 v2 = W4[(size_t)(r + 4) * 128 + q];
        float4 v3 = W4[(size_t)(r + 6) * 128 + q];
        a0.x += v0.x; a0.y += v0.y; a0.z += v0.z; a0.w += v0.w;
        a1.x += v1.x; a1.y += v1.y; a1.z += v1.z; a1.w += v1.w;
        a2.x += v2.x; a2.y += v2.y; a2.z += v2.z; a2.w += v2.w;
        a3.x += v3.x; a3.y += v3.y; a3.z += v3.z; a3.w += v3.w;
    }
    for (; r < r1; r += 2) {
        float4 v = W4[(size_t)r * 128 + q];
        a0.x += v.x; a0.y += v.y; a0.z += v.z; a0.w += v.w;
    }
    a0.x += a1.x + a2.x + a3.x;
    a0.y += a1.y + a2.y + a3.y;
    a0.z += a1.z + a2.z + a3.z;
    a0.w += a1.w + a2.w + a3.w;

    __shared__ float4 smem[128];
    if (rsub) smem[q] = a0;
    __syncthreads();
    if (!rsub) {
        float4 o = smem[q];
        a0.x += o.x; a0.y += o.y; a0.z += o.z; a0.w += o.w;
        partialT[(size_t)q * NB1 + b] = a0;   // empty blocks write zeros
    }
}

// K2: colsum quad q = sum of partialT[q*NB1 .. +1023]. Block 0 also zeroes
// the scalar accumulators (sums, out) consumed downstream — replaces memsets.
__global__ __launch_bounds__(256, 4)
void colsum_reduce(const float4* __restrict__ partialT, float* __restrict__ colsum,
                   float* __restrict__ sums, float* __restrict__ out) {
    const int q = blockIdx.x;       // 0..127
    const int t = threadIdx.x;
    if (q == 0 && t < 3) {
        if (t < 2) sums[t] = 0.0f;
        else *out = 0.0f;
    }
    const float4* __restrict__ p = partialT + (size_t)q * NB1;
    float4 v0 = p[t], v1 = p[t + 256], v2 = p[t + 512], v3 = p[t + 768];
    float sx = (v0.x + v1.x) + (v2.x + v3.x);
    float sy = (v0.y + v1.y) + (v2.y + v3.y);
    float sz = (v0.z + v1.z) + (v2.z + v3.z);
    float sw = (v0.w + v1.w) + (v2.w + v3.w);
    sx = wave_reduce(sx); sy = wave_reduce(sy);
    sz = wave_reduce(sz); sw = wave_reduce(sw);
    __shared__ float4 sm[4];
    if ((t & 63) == 0) sm[t >> 6] = make_float4(sx, sy, sz, sw);
    __syncthreads();
    if (t == 0) {
        float4 r0 = sm[0], r1 = sm[1], r2 = sm[2], r3 = sm[3];
        colsum[q * 4 + 0] = (r0.x + r1.x) + (r2.x + r3.x);
        colsum[q * 4 + 1] = (r0.y + r1.y) + (r2.y + r3.y);
        colsum[q * 4 + 2] = (r0.z + r1.z) + (r2.z + r3.z);
        colsum[q * 4 + 3] = (r0.w + r1.w) + (r2.w + r3.w);
    }
}

// K3: Sy = sum (wy-mu)^2 ; Si = sum (colsum - wy - mu)^2   over B*D elements
__global__ void dist_kernel(const float* __restrict__ mu,
                            const float* __restrict__ W,
                            const int*   __restrict__ label,
                            const float* __restrict__ colsum,
                            float* __restrict__ sums) {
    __shared__ float smem[8];
    float dy2 = 0.0f, di2 = 0.0f;
    const int n = BDIM * DDIM;
    for (int i = blockIdx.x * blockDim.x + threadIdx.x; i < n;
         i += gridDim.x * blockDim.x) {
        const int b = i >> 9;        // i / 512
        const int d = i & 511;       // i % 512
        const float w = W[(size_t)label[b] * DDIM + d];
        const float m = mu[i];
        const float a = w - m;
        dy2 += a * a;
        const float c = colsum[d] - w - m;
        di2 += c * c;
    }
    dy2 = block_reduce(dy2, smem);
    __syncthreads();
    di2 = block_reduce(di2, smem);
    if (threadIdx.x == 0) {
        atomicAdd(&sums[0], dy2);
        atomicAdd(&sums[1], di2);
    }
}

// K4: loss = sum erf(dy/(sqrt2*std)) + erfc(di/(sqrt2*std))
__global__ void loss_kernel(const float* __restrict__ stdv,
                            const float* __restrict__ sums,
                            float* __restrict__ out) {
    __shared__ float smem[8];
    const float dy = sqrtf(sums[0]);
    const float di = sqrtf(sums[1]);
    const float inv_sqrt2 = 0.70710678118654752f;
    float acc = 0.0f;
    const int n = BDIM * DDIM;
    for (int i = blockIdx.x * blockDim.x + threadIdx.x; i < n;
         i += gridDim.x * blockDim.x) {
        const float s = stdv[i];
        const float r = inv_sqrt2 / s;
        acc += erff(dy * r) + erfcf(di * r);
    }
    acc = block_reduce(acc, smem);
    if (threadIdx.x == 0) atomicAdd(out, acc);
}

extern "C" void kernel_launch(void* const* d_in, const int* in_sizes, int n_in,
                              void* d_out, int out_size, void* d_ws, size_t ws_size,
                              hipStream_t stream) {
    // inputs: 0=x (unused), 1=mu, 2=std, 3=weight, 4=label
    const float* mu    = (const float*)d_in[1];
    const float* stdv  = (const float*)d_in[2];
    const float* W     = (const float*)d_in[3];
    const int*   label = (const int*)d_in[4];
    float* out = (float*)d_out;
    float* ws  = (float*)d_ws;
    // ws layout: [0..511]=colsum, [512],[513]=Sy,Si, floats [1024 ...) = partialT (2 MB)
    float4* partialT = (float4*)(ws + 1024);

    colsum_partial<<<NB1, 256, 0, stream>>>(W, partialT);
    colsum_reduce<<<128, 256, 0, stream>>>(partialT, ws, ws + 512, out);
    dist_kernel<<<256, 256, 0, stream>>>(mu, W, label, ws, ws + 512);
    loss_kernel<<<256, 256, 0, stream>>>(stdv, ws + 512, out);
}